// Round 1
// baseline (1063.189 us; speedup 1.0000x reference)
//
#include <hip/hip_runtime.h>
#include <stdint.h>
#include <math.h>

typedef unsigned short u16;
typedef __attribute__((ext_vector_type(4))) unsigned short u16x4;
typedef __attribute__((ext_vector_type(8))) short short8;
typedef __attribute__((ext_vector_type(4))) float floatx4;

#define B_TOK 4096
#define H_DIM 1024
#define D_DIM 4096
#define E_NUM 8
#define PAIR_CAP 9216   // 8192 pairs + up to 8*128 alignment padding

// ---------------- helpers ----------------

__device__ __forceinline__ u16 f2bf(float f) {
  union { float f; uint32_t u; } v; v.f = f;
  uint32_t r = (v.u + 0x7fffu + ((v.u >> 16) & 1u)) >> 16;
  return (u16)r;
}

__device__ __forceinline__ void gload_lds16(const u16* g, u16* l) {
  __builtin_amdgcn_global_load_lds((const __attribute__((address_space(1))) void*)g,
                                   (__attribute__((address_space(3))) void*)l, 16, 0, 0);
}

// ---------------- gating (fp32 exact) ----------------

__global__ __launch_bounds__(256) void gate_kernel(
    const float* __restrict__ x, const float* __restrict__ gw, const float* __restrict__ gb,
    int* __restrict__ counts, float* __restrict__ prob_sum,
    int* __restrict__ tidx, float* __restrict__ tscale) {
  int wave = threadIdx.x >> 6, lane = threadIdx.x & 63;
  int b = blockIdx.x * 4 + wave;
  const float* xr = x + (size_t)b * H_DIM;
  float acc[8] = {0.f,0.f,0.f,0.f,0.f,0.f,0.f,0.f};
  for (int i = 0; i < 16; i++) {
    int h = lane + i * 64;
    float xv = xr[h];
    const float* g = gw + h * 8;
    #pragma unroll
    for (int e = 0; e < 8; e++) acc[e] += xv * g[e];
  }
  #pragma unroll
  for (int e = 0; e < 8; e++) {
    #pragma unroll
    for (int off = 32; off > 0; off >>= 1) acc[e] += __shfl_down(acc[e], off);
  }
  if (lane == 0) {
    float p[8], m = -1e30f, s = 0.f;
    #pragma unroll
    for (int e = 0; e < 8; e++) { p[e] = acc[e] + gb[e]; m = fmaxf(m, p[e]); }
    #pragma unroll
    for (int e = 0; e < 8; e++) { p[e] = expf(p[e] - m); s += p[e]; }
    float inv = 1.f / s;
    #pragma unroll
    for (int e = 0; e < 8; e++) p[e] *= inv;
    int i1 = 0;
    #pragma unroll
    for (int e = 1; e < 8; e++) if (p[e] > p[i1]) i1 = e;
    int i2 = (i1 == 0) ? 1 : 0;
    #pragma unroll
    for (int e = 0; e < 8; e++) if (e != i1 && p[e] > p[i2]) i2 = e;
    tidx[2*b]     = i1; tscale[2*b]     = p[i1] * 0.5f;
    tidx[2*b + 1] = i2; tscale[2*b + 1] = p[i2] * 0.5f;
    atomicAdd(&counts[i1], 1);
    atomicAdd(&counts[i2], 1);
    #pragma unroll
    for (int e = 0; e < 8; e++) atomicAdd(&prob_sum[e], p[e]);
  }
}

// ---------------- offsets + aux loss + pair init ----------------

__global__ void offsets_kernel(const int* __restrict__ counts, const float* __restrict__ prob_sum,
                               int* __restrict__ offs, int* __restrict__ ptok,
                               float* __restrict__ pscale, float* __restrict__ aux_out) {
  if (threadIdx.x == 0) {
    int o = 0;
    float aux = 0.f;
    for (int e = 0; e < 8; e++) {
      offs[e] = o;
      o += ((counts[e] + 127) >> 7) << 7;          // 128-aligned regions
      aux += (prob_sum[e] * (1.f / 4096.f)) * ((float)counts[e] * (1.f / 4096.f));
    }
    offs[8] = o;
    aux_out[0] = aux * 8.f;
  }
  for (int i = threadIdx.x; i < PAIR_CAP; i += 256) { ptok[i] = 0; pscale[i] = 0.f; }
}

// ---------------- scatter tokens into expert-sorted pair list ----------------

__global__ __launch_bounds__(256) void scatter_kernel(
    const int* __restrict__ tidx, const float* __restrict__ tscale,
    const int* __restrict__ offs, int* __restrict__ fill,
    int* __restrict__ ptok, float* __restrict__ pscale) {
  int b = blockIdx.x * 256 + threadIdx.x;
  #pragma unroll
  for (int k = 0; k < 2; k++) {
    int e = tidx[2*b + k];
    int pos = offs[e] + atomicAdd(&fill[e], 1);
    ptok[pos] = b;
    pscale[pos] = tscale[2*b + k];
  }
}

// ---------------- fp32 -> bf16 convert (x) ----------------

__global__ __launch_bounds__(256) void convert_x(const float* __restrict__ in, u16* __restrict__ out) {
  int i = blockIdx.x * 256 + threadIdx.x;   // grid covers exactly B*H/4
  float4 v = ((const float4*)in)[i];
  u16x4 o;
  o[0] = f2bf(v.x); o[1] = f2bf(v.y); o[2] = f2bf(v.z); o[3] = f2bf(v.w);
  ((u16x4*)out)[i] = o;
}

// ---------------- fp32 [R][C] -> bf16 transposed [C][R], per expert (blockIdx.z) ----------------

__global__ __launch_bounds__(256) void transpose_convert(
    const float* __restrict__ in, u16* __restrict__ out, int R, int C) {
  __shared__ u16 tile[64 * 65];
  size_t eoff = (size_t)blockIdx.z * R * C;
  const float* inp = in + eoff;
  u16* outp = out + eoff;
  int c0 = blockIdx.x * 64, r0 = blockIdx.y * 64;
  int t = threadIdx.x;
  int rr = t >> 4, cc = t & 15;
  #pragma unroll
  for (int p = 0; p < 4; p++) {
    int r = rr + p * 16;
    float4 v = *(const float4*)(inp + (size_t)(r0 + r) * C + c0 + cc * 4);
    int base = r * 65 + cc * 4;
    tile[base + 0] = f2bf(v.x); tile[base + 1] = f2bf(v.y);
    tile[base + 2] = f2bf(v.z); tile[base + 3] = f2bf(v.w);
  }
  __syncthreads();
  #pragma unroll
  for (int p = 0; p < 4; p++) {
    int c = rr + p * 16;
    u16x4 w;
    w[0] = tile[(cc*4 + 0) * 65 + c];
    w[1] = tile[(cc*4 + 1) * 65 + c];
    w[2] = tile[(cc*4 + 2) * 65 + c];
    w[3] = tile[(cc*4 + 3) * 65 + c];
    *(u16x4*)(outp + (size_t)(c0 + c) * R + r0 + cc * 4) = w;
  }
}

// ---------------- grouped GEMM (m97 structure: 128x128 tile, BK=32, global_load_lds w16) ----
// FIRST : h[pair][D] = relu( x_bf[token(pair)][H] @ w1t[e][D][H]^T + b1[e] )  (store bf16)
// !FIRST: y[token]   += scale(pair) * ( h[pair][D] @ w2t[e][H][D]^T + b2[e] ) (atomic fp32)

template <bool FIRST>
__global__ __launch_bounds__(256, 2) void moe_gemm(
    const u16* __restrict__ A, const u16* __restrict__ Bw, const float* __restrict__ bias,
    const int* __restrict__ ptok, const float* __restrict__ pscale,
    const int* __restrict__ offs, u16* __restrict__ Hout, float* __restrict__ Y) {
  constexpr int KD = FIRST ? H_DIM : D_DIM;   // reduction dim
  constexpr int ND = FIRST ? D_DIM : H_DIM;   // output cols
  constexpr int AS = FIRST ? H_DIM : D_DIM;   // A row stride

  const int row0 = blockIdx.y * 128;
  const int total = offs[8];
  if (row0 >= total) return;
  int e = 0;
  #pragma unroll
  for (int q = 0; q < 7; q++) if (row0 >= offs[q + 1]) e = q + 1;

  const int n0 = blockIdx.x * 128;
  const int t = threadIdx.x;

  __shared__ __align__(16) u16 lA[128 * 32];
  __shared__ __align__(16) u16 lB[128 * 32];

  // staging addresses: flat chunk id = t (+256), row = flat>>2, 16B chunk = flat&3
  const int rA0 = row0 + (t >> 2);
  const int rA1 = rA0 + 64;
  size_t aoff0, aoff1;
  if (FIRST) {
    aoff0 = (size_t)ptok[rA0] * AS;
    aoff1 = (size_t)ptok[rA1] * AS;
  } else {
    aoff0 = (size_t)rA0 * AS;
    aoff1 = (size_t)rA1 * AS;
  }
  const u16* gA0 = A + aoff0 + (t & 3) * 8;
  const u16* gA1 = A + aoff1 + (t & 3) * 8;
  const u16* Be = Bw + (size_t)e * (H_DIM * D_DIM);
  const u16* gB0 = Be + (size_t)(n0 + (t >> 2)) * KD + (t & 3) * 8;
  const u16* gB1 = gB0 + (size_t)64 * KD;
  u16* dA0 = &lA[t * 8];       u16* dA1 = &lA[(t + 256) * 8];
  u16* dB0 = &lB[t * 8];       u16* dB1 = &lB[(t + 256) * 8];

  const int wave = t >> 6, lane = t & 63;
  const int wr = (wave >> 1) * 64, wc = (wave & 1) * 64;
  const int fr = lane & 15, fg = lane >> 4;

  floatx4 acc[4][4];
  #pragma unroll
  for (int i = 0; i < 4; i++)
    #pragma unroll
    for (int j = 0; j < 4; j++) acc[i][j] = (floatx4){0.f, 0.f, 0.f, 0.f};

  for (int k0 = 0; k0 < KD; k0 += 32) {
    gload_lds16(gA0 + k0, dA0);
    gload_lds16(gA1 + k0, dA1);
    gload_lds16(gB0 + k0, dB0);
    gload_lds16(gB1 + k0, dB1);
    __syncthreads();
    short8 af[4], bf[4];
    #pragma unroll
    for (int i = 0; i < 4; i++) af[i] = *(const short8*)&lA[(wr + i * 16 + fr) * 32 + fg * 8];
    #pragma unroll
    for (int j = 0; j < 4; j++) bf[j] = *(const short8*)&lB[(wc + j * 16 + fr) * 32 + fg * 8];
    #pragma unroll
    for (int i = 0; i < 4; i++)
      #pragma unroll
      for (int j = 0; j < 4; j++)
        acc[i][j] = __builtin_amdgcn_mfma_f32_16x16x32_bf16(af[i], bf[j], acc[i][j], 0, 0, 0);
    __syncthreads();
  }

  if (FIRST) {
    const float* be = bias + (size_t)e * ND;
    #pragma unroll
    for (int i = 0; i < 4; i++) {
      #pragma unroll
      for (int r = 0; r < 4; r++) {
        int row = row0 + wr + i * 16 + fg * 4 + r;
        u16* hrow = Hout + (size_t)row * ND;
        #pragma unroll
        for (int j = 0; j < 4; j++) {
          int col = n0 + wc + j * 16 + fr;
          float v = acc[i][j][r] + be[col];
          hrow[col] = f2bf(fmaxf(v, 0.f));
        }
      }
    }
  } else {
    const float* be = bias + (size_t)e * ND;
    #pragma unroll
    for (int i = 0; i < 4; i++) {
      #pragma unroll
      for (int r = 0; r < 4; r++) {
        int row = row0 + wr + i * 16 + fg * 4 + r;
        float sc = pscale[row];
        if (sc != 0.f) {
          int tok = ptok[row];
          float* yrow = Y + (size_t)tok * ND;
          #pragma unroll
          for (int j = 0; j < 4; j++) {
            int col = n0 + wc + j * 16 + fr;
            atomicAdd(&yrow[col], (acc[i][j][r] + be[col]) * sc);
          }
        }
      }
    }
  }
}

// ---------------- launch ----------------

extern "C" void kernel_launch(void* const* d_in, const int* in_sizes, int n_in,
                              void* d_out, int out_size, void* d_ws, size_t ws_size,
                              hipStream_t stream) {
  const float* x      = (const float*)d_in[0];
  const float* gate_w = (const float*)d_in[1];
  const float* gate_b = (const float*)d_in[2];
  const float* w1     = (const float*)d_in[3];
  const float* b1     = (const float*)d_in[4];
  const float* w2     = (const float*)d_in[5];
  const float* b2     = (const float*)d_in[6];
  float* out = (float*)d_out;

  char* ws = (char*)d_ws;
  u16*   x_bf   = (u16*)  (ws);                 //   8,388,608 B
  u16*   w1t    = (u16*)  (ws + 8388608);       //  67,108,864 B  [E][D][H]
  u16*   w2t    = (u16*)  (ws + 75497472);      //  67,108,864 B  [E][H][D]
  u16*   h_bf   = (u16*)  (ws + 142606336);     //  75,497,472 B  [PAIR_CAP][D]
  int*   ptok   = (int*)  (ws + 218103808);     //  PAIR_CAP ints
  float* pscale = (float*)(ws + 218140672);     //  PAIR_CAP floats
  int*   tidx   = (int*)  (ws + 218177536);     //  B*2 ints
  float* tscale = (float*)(ws + 218210304);     //  B*2 floats
  int*   ctr    = (int*)  (ws + 218243072);
  int*   counts   = ctr;            // [0..7]
  int*   fill     = ctr + 8;        // [8..15]
  float* prob_sum = (float*)(ctr + 16); // [16..23]
  int*   offs     = ctr + 24;       // [24..32]

  hipMemsetAsync(d_out, 0, (size_t)out_size * sizeof(float), stream);
  hipMemsetAsync(ctr, 0, 24 * sizeof(int), stream);

  convert_x<<<(B_TOK * H_DIM) / 4 / 256, 256, 0, stream>>>(x, x_bf);
  transpose_convert<<<dim3(D_DIM / 64, H_DIM / 64, E_NUM), 256, 0, stream>>>(w1, w1t, H_DIM, D_DIM);
  transpose_convert<<<dim3(H_DIM / 64, D_DIM / 64, E_NUM), 256, 0, stream>>>(w2, w2t, D_DIM, H_DIM);
  gate_kernel<<<B_TOK / 4, 256, 0, stream>>>(x, gate_w, gate_b, counts, prob_sum, tidx, tscale);
  offsets_kernel<<<1, 256, 0, stream>>>(counts, prob_sum, offs, ptok, pscale, out + (size_t)B_TOK * H_DIM);
  scatter_kernel<<<B_TOK / 256, 256, 0, stream>>>(tidx, tscale, offs, fill, ptok, pscale);
  moe_gemm<true><<<dim3(D_DIM / 128, PAIR_CAP / 128), 256, 0, stream>>>(
      x_bf, w1t, b1, ptok, pscale, offs, h_bf, nullptr);
  moe_gemm<false><<<dim3(H_DIM / 128, PAIR_CAP / 128), 256, 0, stream>>>(
      h_bf, w2t, b2, ptok, pscale, offs, nullptr, out);
}

// Round 2
// 617.739 us; speedup vs baseline: 1.7211x; 1.7211x over previous
//
#include <hip/hip_runtime.h>
#include <stdint.h>
#include <math.h>

typedef unsigned short u16;
typedef __attribute__((ext_vector_type(4))) unsigned short u16x4;
typedef __attribute__((ext_vector_type(8))) short short8;
typedef __attribute__((ext_vector_type(4))) float floatx4;

#define B_TOK 4096
#define H_DIM 1024
#define D_DIM 4096
#define E_NUM 8
#define PAIR_CAP 9216   // 8192 pairs + up to 8*128 alignment padding
#define GATE_BLOCKS 256

// ---------------- helpers ----------------

__device__ __forceinline__ u16 f2bf(float f) {
  union { float f; uint32_t u; } v; v.f = f;
  uint32_t r = (v.u + 0x7fffu + ((v.u >> 16) & 1u)) >> 16;
  return (u16)r;
}

__device__ __forceinline__ void gload_lds16(const u16* g, u16* l) {
  __builtin_amdgcn_global_load_lds((const __attribute__((address_space(1))) void*)g,
                                   (__attribute__((address_space(3))) void*)l, 16, 0, 0);
}

// ---------------- gating (fp32 exact, NO hot global atomics) ----------------
// 256 blocks x 4 waves; each wave processes 4 tokens (grid-stride). Per-wave
// register partials -> LDS block reduce -> per-block partial slot in ws.

__global__ __launch_bounds__(256) void gate_kernel(
    const float* __restrict__ x, const float* __restrict__ gw, const float* __restrict__ gb,
    int* __restrict__ pcnt, float* __restrict__ psum,
    int* __restrict__ tidx, float* __restrict__ tscale) {
  int wave = threadIdx.x >> 6, lane = threadIdx.x & 63;
  __shared__ int scnt[4][8];
  __shared__ float ssum[4][8];
  int lcnt[8] = {0,0,0,0,0,0,0,0};
  float lsum[8] = {0.f,0.f,0.f,0.f,0.f,0.f,0.f,0.f};

  for (int it = 0; it < 4; it++) {
    int b = blockIdx.x * 16 + it * 4 + wave;
    const float* xr = x + (size_t)b * H_DIM;
    float acc[8] = {0.f,0.f,0.f,0.f,0.f,0.f,0.f,0.f};
    for (int i = 0; i < 16; i++) {
      int h = lane + i * 64;
      float xv = xr[h];
      const float* g = gw + h * 8;
      #pragma unroll
      for (int e = 0; e < 8; e++) acc[e] += xv * g[e];
    }
    #pragma unroll
    for (int e = 0; e < 8; e++) {
      #pragma unroll
      for (int off = 32; off > 0; off >>= 1) acc[e] += __shfl_down(acc[e], off);
    }
    if (lane == 0) {
      float p[8], m = -1e30f, s = 0.f;
      #pragma unroll
      for (int e = 0; e < 8; e++) { p[e] = acc[e] + gb[e]; m = fmaxf(m, p[e]); }
      #pragma unroll
      for (int e = 0; e < 8; e++) { p[e] = expf(p[e] - m); s += p[e]; }
      float inv = 1.f / s;
      #pragma unroll
      for (int e = 0; e < 8; e++) { p[e] *= inv; lsum[e] += p[e]; }
      int i1 = 0;
      #pragma unroll
      for (int e = 1; e < 8; e++) if (p[e] > p[i1]) i1 = e;
      int i2 = (i1 == 0) ? 1 : 0;
      #pragma unroll
      for (int e = 0; e < 8; e++) if (e != i1 && p[e] > p[i2]) i2 = e;
      tidx[2*b]     = i1; tscale[2*b]     = p[i1] * 0.5f;
      tidx[2*b + 1] = i2; tscale[2*b + 1] = p[i2] * 0.5f;
      lcnt[i1]++; lcnt[i2]++;
    }
  }
  if (lane == 0) {
    #pragma unroll
    for (int e = 0; e < 8; e++) { scnt[wave][e] = lcnt[e]; ssum[wave][e] = lsum[e]; }
  }
  __syncthreads();
  if (threadIdx.x < 8) {
    int e = threadIdx.x;
    int c = scnt[0][e] + scnt[1][e] + scnt[2][e] + scnt[3][e];
    float s = ssum[0][e] + ssum[1][e] + ssum[2][e] + ssum[3][e];
    pcnt[blockIdx.x * 8 + e] = c;
    psum[blockIdx.x * 8 + e] = s;
  }
}

// ---------------- offsets + aux loss + pair init ----------------

__global__ __launch_bounds__(256) void offsets_kernel(
    const int* __restrict__ pcnt, const float* __restrict__ psum,
    int* __restrict__ offs, int* __restrict__ ptok,
    float* __restrict__ pscale, float* __restrict__ aux_out) {
  __shared__ int cnt[8];
  __shared__ float ps[8];
  if (threadIdx.x < 8) {
    int e = threadIdx.x;
    int c = 0; float s = 0.f;
    for (int i = 0; i < GATE_BLOCKS; i++) { c += pcnt[i * 8 + e]; s += psum[i * 8 + e]; }
    cnt[e] = c; ps[e] = s;
  }
  __syncthreads();
  if (threadIdx.x == 0) {
    int o = 0;
    float aux = 0.f;
    for (int e = 0; e < 8; e++) {
      offs[e] = o;
      o += ((cnt[e] + 127) >> 7) << 7;          // 128-aligned regions
      aux += (ps[e] * (1.f / 4096.f)) * ((float)cnt[e] * (1.f / 4096.f));
    }
    offs[8] = o;
    aux_out[0] = aux * 8.f;
  }
  for (int i = threadIdx.x; i < PAIR_CAP; i += 256) { ptok[i] = 0; pscale[i] = 0.f; }
}

// ---------------- scatter: LDS histogram + one batched global atomic per expert per block ----

__global__ __launch_bounds__(256) void scatter_kernel(
    const int* __restrict__ tidx, const float* __restrict__ tscale,
    const int* __restrict__ offs, int* __restrict__ fill,
    int* __restrict__ ptok, float* __restrict__ pscale) {
  __shared__ int lcnt[8];
  __shared__ int lbase[8];
  if (threadIdx.x < 8) lcnt[threadIdx.x] = 0;
  __syncthreads();
  int b = blockIdx.x * 256 + threadIdx.x;
  int e0 = tidx[2*b], e1 = tidx[2*b + 1];
  int p0 = atomicAdd(&lcnt[e0], 1);
  int p1 = atomicAdd(&lcnt[e1], 1);
  __syncthreads();
  if (threadIdx.x < 8) {
    int e = threadIdx.x;
    lbase[e] = offs[e] + atomicAdd(&fill[e], lcnt[e]);
  }
  __syncthreads();
  int pos0 = lbase[e0] + p0;
  int pos1 = lbase[e1] + p1;
  ptok[pos0] = b; pscale[pos0] = tscale[2*b];
  ptok[pos1] = b; pscale[pos1] = tscale[2*b + 1];
}

// ---------------- fp32 -> bf16 convert (x) ----------------

__global__ __launch_bounds__(256) void convert_x(const float* __restrict__ in, u16* __restrict__ out) {
  int i = blockIdx.x * 256 + threadIdx.x;   // grid covers exactly B*H/4
  float4 v = ((const float4*)in)[i];
  u16x4 o;
  o[0] = f2bf(v.x); o[1] = f2bf(v.y); o[2] = f2bf(v.z); o[3] = f2bf(v.w);
  ((u16x4*)out)[i] = o;
}

// ---------------- fp32 [R][C] -> bf16 transposed [C][R], per expert (blockIdx.z) ----------------

__global__ __launch_bounds__(256) void transpose_convert(
    const float* __restrict__ in, u16* __restrict__ out, int R, int C) {
  __shared__ u16 tile[64 * 65];
  size_t eoff = (size_t)blockIdx.z * R * C;
  const float* inp = in + eoff;
  u16* outp = out + eoff;
  int c0 = blockIdx.x * 64, r0 = blockIdx.y * 64;
  int t = threadIdx.x;
  int rr = t >> 4, cc = t & 15;
  #pragma unroll
  for (int p = 0; p < 4; p++) {
    int r = rr + p * 16;
    float4 v = *(const float4*)(inp + (size_t)(r0 + r) * C + c0 + cc * 4);
    int base = r * 65 + cc * 4;
    tile[base + 0] = f2bf(v.x); tile[base + 1] = f2bf(v.y);
    tile[base + 2] = f2bf(v.z); tile[base + 3] = f2bf(v.w);
  }
  __syncthreads();
  #pragma unroll
  for (int p = 0; p < 4; p++) {
    int c = rr + p * 16;
    u16x4 w;
    w[0] = tile[(cc*4 + 0) * 65 + c];
    w[1] = tile[(cc*4 + 1) * 65 + c];
    w[2] = tile[(cc*4 + 2) * 65 + c];
    w[3] = tile[(cc*4 + 3) * 65 + c];
    *(u16x4*)(outp + (size_t)(c0 + c) * R + r0 + cc * 4) = w;
  }
}

// ---------------- grouped GEMM (m97 structure: 128x128 tile, BK=32, global_load_lds w16) ----
// FIRST : h[pair][D] = relu( x_bf[token(pair)][H] @ w1t[e][D][H]^T + b1[e] )  (store bf16)
// !FIRST: y[token]   += scale(pair) * ( h[pair][D] @ w2t[e][H][D]^T + b2[e] ) (atomic fp32)

template <bool FIRST>
__global__ __launch_bounds__(256, 2) void moe_gemm(
    const u16* __restrict__ A, const u16* __restrict__ Bw, const float* __restrict__ bias,
    const int* __restrict__ ptok, const float* __restrict__ pscale,
    const int* __restrict__ offs, u16* __restrict__ Hout, float* __restrict__ Y) {
  constexpr int KD = FIRST ? H_DIM : D_DIM;   // reduction dim
  constexpr int ND = FIRST ? D_DIM : H_DIM;   // output cols
  constexpr int AS = FIRST ? H_DIM : D_DIM;   // A row stride

  const int row0 = blockIdx.y * 128;
  const int total = offs[8];
  if (row0 >= total) return;
  int e = 0;
  #pragma unroll
  for (int q = 0; q < 7; q++) if (row0 >= offs[q + 1]) e = q + 1;

  const int n0 = blockIdx.x * 128;
  const int t = threadIdx.x;

  __shared__ __align__(16) u16 lA[128 * 32];
  __shared__ __align__(16) u16 lB[128 * 32];

  // staging addresses: flat chunk id = t (+256), row = flat>>2, 16B chunk = flat&3
  const int rA0 = row0 + (t >> 2);
  const int rA1 = rA0 + 64;
  size_t aoff0, aoff1;
  if (FIRST) {
    aoff0 = (size_t)ptok[rA0] * AS;
    aoff1 = (size_t)ptok[rA1] * AS;
  } else {
    aoff0 = (size_t)rA0 * AS;
    aoff1 = (size_t)rA1 * AS;
  }
  const u16* gA0 = A + aoff0 + (t & 3) * 8;
  const u16* gA1 = A + aoff1 + (t & 3) * 8;
  const u16* Be = Bw + (size_t)e * (H_DIM * D_DIM);
  const u16* gB0 = Be + (size_t)(n0 + (t >> 2)) * KD + (t & 3) * 8;
  const u16* gB1 = gB0 + (size_t)64 * KD;
  u16* dA0 = &lA[t * 8];       u16* dA1 = &lA[(t + 256) * 8];
  u16* dB0 = &lB[t * 8];       u16* dB1 = &lB[(t + 256) * 8];

  const int wave = t >> 6, lane = t & 63;
  const int wr = (wave >> 1) * 64, wc = (wave & 1) * 64;
  const int fr = lane & 15, fg = lane >> 4;

  floatx4 acc[4][4];
  #pragma unroll
  for (int i = 0; i < 4; i++)
    #pragma unroll
    for (int j = 0; j < 4; j++) acc[i][j] = (floatx4){0.f, 0.f, 0.f, 0.f};

  for (int k0 = 0; k0 < KD; k0 += 32) {
    gload_lds16(gA0 + k0, dA0);
    gload_lds16(gA1 + k0, dA1);
    gload_lds16(gB0 + k0, dB0);
    gload_lds16(gB1 + k0, dB1);
    __syncthreads();
    short8 af[4], bf[4];
    #pragma unroll
    for (int i = 0; i < 4; i++) af[i] = *(const short8*)&lA[(wr + i * 16 + fr) * 32 + fg * 8];
    #pragma unroll
    for (int j = 0; j < 4; j++) bf[j] = *(const short8*)&lB[(wc + j * 16 + fr) * 32 + fg * 8];
    #pragma unroll
    for (int i = 0; i < 4; i++)
      #pragma unroll
      for (int j = 0; j < 4; j++)
        acc[i][j] = __builtin_amdgcn_mfma_f32_16x16x32_bf16(af[i], bf[j], acc[i][j], 0, 0, 0);
    __syncthreads();
  }

  if (FIRST) {
    const float* be = bias + (size_t)e * ND;
    #pragma unroll
    for (int i = 0; i < 4; i++) {
      #pragma unroll
      for (int r = 0; r < 4; r++) {
        int row = row0 + wr + i * 16 + fg * 4 + r;
        u16* hrow = Hout + (size_t)row * ND;
        #pragma unroll
        for (int j = 0; j < 4; j++) {
          int col = n0 + wc + j * 16 + fr;
          float v = acc[i][j][r] + be[col];
          hrow[col] = f2bf(fmaxf(v, 0.f));
        }
      }
    }
  } else {
    const float* be = bias + (size_t)e * ND;
    #pragma unroll
    for (int i = 0; i < 4; i++) {
      #pragma unroll
      for (int r = 0; r < 4; r++) {
        int row = row0 + wr + i * 16 + fg * 4 + r;
        float sc = pscale[row];
        if (sc != 0.f) {
          int tok = ptok[row];
          float* yrow = Y + (size_t)tok * ND;
          #pragma unroll
          for (int j = 0; j < 4; j++) {
            int col = n0 + wc + j * 16 + fr;
            atomicAdd(&yrow[col], (acc[i][j][r] + be[col]) * sc);
          }
        }
      }
    }
  }
}

// ---------------- launch ----------------

extern "C" void kernel_launch(void* const* d_in, const int* in_sizes, int n_in,
                              void* d_out, int out_size, void* d_ws, size_t ws_size,
                              hipStream_t stream) {
  const float* x      = (const float*)d_in[0];
  const float* gate_w = (const float*)d_in[1];
  const float* gate_b = (const float*)d_in[2];
  const float* w1     = (const float*)d_in[3];
  const float* b1     = (const float*)d_in[4];
  const float* w2     = (const float*)d_in[5];
  const float* b2     = (const float*)d_in[6];
  float* out = (float*)d_out;

  char* ws = (char*)d_ws;
  u16*   x_bf   = (u16*)  (ws);                 //   8,388,608 B
  u16*   w1t    = (u16*)  (ws + 8388608);       //  67,108,864 B  [E][D][H]
  u16*   w2t    = (u16*)  (ws + 75497472);      //  67,108,864 B  [E][H][D]
  u16*   h_bf   = (u16*)  (ws + 142606336);     //  75,497,472 B  [PAIR_CAP][D]
  int*   ptok   = (int*)  (ws + 218103808);     //  PAIR_CAP ints
  float* pscale = (float*)(ws + 218140672);     //  PAIR_CAP floats
  int*   tidx   = (int*)  (ws + 218177536);     //  B*2 ints
  float* tscale = (float*)(ws + 218210304);     //  B*2 floats
  int*   ctr    = (int*)  (ws + 218243072);
  int*   fill     = ctr;            // [0..7]
  int*   offs     = ctr + 8;        // [8..16]
  int*   pcnt     = ctr + 32;       // [32 .. 32+GATE_BLOCKS*8)
  float* psum     = (float*)(ctr + 32 + GATE_BLOCKS * 8);  // GATE_BLOCKS*8 floats

  hipMemsetAsync(d_out, 0, (size_t)out_size * sizeof(float), stream);
  hipMemsetAsync(fill, 0, 8 * sizeof(int), stream);

  convert_x<<<(B_TOK * H_DIM) / 4 / 256, 256, 0, stream>>>(x, x_bf);
  transpose_convert<<<dim3(D_DIM / 64, H_DIM / 64, E_NUM), 256, 0, stream>>>(w1, w1t, H_DIM, D_DIM);
  transpose_convert<<<dim3(H_DIM / 64, D_DIM / 64, E_NUM), 256, 0, stream>>>(w2, w2t, D_DIM, H_DIM);
  gate_kernel<<<GATE_BLOCKS, 256, 0, stream>>>(x, gate_w, gate_b, pcnt, psum, tidx, tscale);
  offsets_kernel<<<1, 256, 0, stream>>>(pcnt, psum, offs, ptok, pscale, out + (size_t)B_TOK * H_DIM);
  scatter_kernel<<<B_TOK / 256, 256, 0, stream>>>(tidx, tscale, offs, fill, ptok, pscale);
  moe_gemm<true><<<dim3(D_DIM / 128, PAIR_CAP / 128), 256, 0, stream>>>(
      x_bf, w1t, b1, ptok, pscale, offs, h_bf, nullptr);
  moe_gemm<false><<<dim3(H_DIM / 128, PAIR_CAP / 128), 256, 0, stream>>>(
      h_bf, w2t, b2, ptok, pscale, offs, nullptr, out);
}

// Round 3
// 610.272 us; speedup vs baseline: 1.7422x; 1.0122x over previous
//
#include <hip/hip_runtime.h>
#include <stdint.h>
#include <math.h>

typedef unsigned short u16;
typedef __attribute__((ext_vector_type(4))) unsigned short u16x4;
typedef __attribute__((ext_vector_type(8))) short short8;
typedef __attribute__((ext_vector_type(4))) float floatx4;

#define B_TOK 4096
#define H_DIM 1024
#define D_DIM 4096
#define E_NUM 8
#define PAIR_CAP 9216   // 8192 pairs + up to 8*128 alignment padding
#define GATE_BLOCKS 256

// ---------------- helpers ----------------

__device__ __forceinline__ u16 f2bf(float f) {
  union { float f; uint32_t u; } v; v.f = f;
  uint32_t r = (v.u + 0x7fffu + ((v.u >> 16) & 1u)) >> 16;
  return (u16)r;
}

__device__ __forceinline__ void gload_lds16(const u16* g, u16* l) {
  __builtin_amdgcn_global_load_lds((const __attribute__((address_space(1))) void*)g,
                                   (__attribute__((address_space(3))) void*)l, 16, 0, 0);
}

// ---------------- gating (fp32 exact, no hot global atomics) ----------------

__global__ __launch_bounds__(256) void gate_kernel(
    const float* __restrict__ x, const float* __restrict__ gw, const float* __restrict__ gb,
    int* __restrict__ pcnt, float* __restrict__ psum,
    int* __restrict__ tidx, float* __restrict__ tscale) {
  int wave = threadIdx.x >> 6, lane = threadIdx.x & 63;
  __shared__ int scnt[4][8];
  __shared__ float ssum[4][8];
  int lcnt[8] = {0,0,0,0,0,0,0,0};
  float lsum[8] = {0.f,0.f,0.f,0.f,0.f,0.f,0.f,0.f};

  for (int it = 0; it < 4; it++) {
    int b = blockIdx.x * 16 + it * 4 + wave;
    const float* xr = x + (size_t)b * H_DIM;
    float acc[8] = {0.f,0.f,0.f,0.f,0.f,0.f,0.f,0.f};
    for (int i = 0; i < 16; i++) {
      int h = lane + i * 64;
      float xv = xr[h];
      const float* g = gw + h * 8;
      #pragma unroll
      for (int e = 0; e < 8; e++) acc[e] += xv * g[e];
    }
    #pragma unroll
    for (int e = 0; e < 8; e++) {
      #pragma unroll
      for (int off = 32; off > 0; off >>= 1) acc[e] += __shfl_down(acc[e], off);
    }
    if (lane == 0) {
      float p[8], m = -1e30f, s = 0.f;
      #pragma unroll
      for (int e = 0; e < 8; e++) { p[e] = acc[e] + gb[e]; m = fmaxf(m, p[e]); }
      #pragma unroll
      for (int e = 0; e < 8; e++) { p[e] = expf(p[e] - m); s += p[e]; }
      float inv = 1.f / s;
      #pragma unroll
      for (int e = 0; e < 8; e++) { p[e] *= inv; lsum[e] += p[e]; }
      int i1 = 0;
      #pragma unroll
      for (int e = 1; e < 8; e++) if (p[e] > p[i1]) i1 = e;
      int i2 = (i1 == 0) ? 1 : 0;
      #pragma unroll
      for (int e = 0; e < 8; e++) if (e != i1 && p[e] > p[i2]) i2 = e;
      tidx[2*b]     = i1; tscale[2*b]     = p[i1] * 0.5f;
      tidx[2*b + 1] = i2; tscale[2*b + 1] = p[i2] * 0.5f;
      lcnt[i1]++; lcnt[i2]++;
    }
  }
  if (lane == 0) {
    #pragma unroll
    for (int e = 0; e < 8; e++) { scnt[wave][e] = lcnt[e]; ssum[wave][e] = lsum[e]; }
  }
  __syncthreads();
  if (threadIdx.x < 8) {
    int e = threadIdx.x;
    int c = scnt[0][e] + scnt[1][e] + scnt[2][e] + scnt[3][e];
    float s = ssum[0][e] + ssum[1][e] + ssum[2][e] + ssum[3][e];
    pcnt[blockIdx.x * 8 + e] = c;
    psum[blockIdx.x * 8 + e] = s;
  }
}

// ---------------- offsets + aux loss + pair init ----------------

__global__ __launch_bounds__(256) void offsets_kernel(
    const int* __restrict__ pcnt, const float* __restrict__ psum,
    int* __restrict__ offs, int* __restrict__ ptok, float* __restrict__ aux_out) {
  __shared__ int cnt[8];
  __shared__ float ps[8];
  if (threadIdx.x < 8) {
    int e = threadIdx.x;
    int c = 0; float s = 0.f;
    for (int i = 0; i < GATE_BLOCKS; i++) { c += pcnt[i * 8 + e]; s += psum[i * 8 + e]; }
    cnt[e] = c; ps[e] = s;
  }
  __syncthreads();
  if (threadIdx.x == 0) {
    int o = 0;
    float aux = 0.f;
    for (int e = 0; e < 8; e++) {
      offs[e] = o;
      o += ((cnt[e] + 127) >> 7) << 7;          // 128-aligned regions
      aux += (ps[e] * (1.f / 4096.f)) * ((float)cnt[e] * (1.f / 4096.f));
    }
    offs[8] = o;
    aux_out[0] = aux * 8.f;
  }
  for (int i = threadIdx.x; i < PAIR_CAP; i += 256) ptok[i] = 0;
}

// ---------------- scatter: LDS histogram + one batched global atomic per expert per block ----

__global__ __launch_bounds__(256) void scatter_kernel(
    const int* __restrict__ tidx, const float* __restrict__ tscale,
    const int* __restrict__ offs, int* __restrict__ fill,
    int* __restrict__ ptok, float* __restrict__ pscale,
    int* __restrict__ pexp, int* __restrict__ pairpos) {
  __shared__ int lcnt[8];
  __shared__ int lbase[8];
  if (threadIdx.x < 8) lcnt[threadIdx.x] = 0;
  __syncthreads();
  int b = blockIdx.x * 256 + threadIdx.x;
  int e0 = tidx[2*b], e1 = tidx[2*b + 1];
  int p0 = atomicAdd(&lcnt[e0], 1);
  int p1 = atomicAdd(&lcnt[e1], 1);
  __syncthreads();
  if (threadIdx.x < 8) {
    int e = threadIdx.x;
    lbase[e] = offs[e] + atomicAdd(&fill[e], lcnt[e]);
  }
  __syncthreads();
  int pos0 = lbase[e0] + p0;
  int pos1 = lbase[e1] + p1;
  ptok[pos0] = b; pscale[pos0] = tscale[2*b];     pexp[pos0] = e0; pairpos[2*b]     = pos0;
  ptok[pos1] = b; pscale[pos1] = tscale[2*b + 1]; pexp[pos1] = e1; pairpos[2*b + 1] = pos1;
}

// ---------------- fp32 -> bf16 convert (x) ----------------

__global__ __launch_bounds__(256) void convert_x(const float* __restrict__ in, u16* __restrict__ out) {
  int i = blockIdx.x * 256 + threadIdx.x;   // grid covers exactly B*H/4
  float4 v = ((const float4*)in)[i];
  u16x4 o;
  o[0] = f2bf(v.x); o[1] = f2bf(v.y); o[2] = f2bf(v.z); o[3] = f2bf(v.w);
  ((u16x4*)out)[i] = o;
}

// ---------------- fp32 [R][C] -> bf16 transposed [C][R], per expert (blockIdx.z) ----------------

__global__ __launch_bounds__(256) void transpose_convert(
    const float* __restrict__ in, u16* __restrict__ out, int R, int C) {
  __shared__ u16 tile[64 * 65];
  size_t eoff = (size_t)blockIdx.z * R * C;
  const float* inp = in + eoff;
  u16* outp = out + eoff;
  int c0 = blockIdx.x * 64, r0 = blockIdx.y * 64;
  int t = threadIdx.x;
  int rr = t >> 4, cc = t & 15;
  #pragma unroll
  for (int p = 0; p < 4; p++) {
    int r = rr + p * 16;
    float4 v = *(const float4*)(inp + (size_t)(r0 + r) * C + c0 + cc * 4);
    int base = r * 65 + cc * 4;
    tile[base + 0] = f2bf(v.x); tile[base + 1] = f2bf(v.y);
    tile[base + 2] = f2bf(v.z); tile[base + 3] = f2bf(v.w);
  }
  __syncthreads();
  #pragma unroll
  for (int p = 0; p < 4; p++) {
    int c = rr + p * 16;
    u16x4 w;
    w[0] = tile[(cc*4 + 0) * 65 + c];
    w[1] = tile[(cc*4 + 1) * 65 + c];
    w[2] = tile[(cc*4 + 2) * 65 + c];
    w[3] = tile[(cc*4 + 3) * 65 + c];
    *(u16x4*)(outp + (size_t)(c0 + c) * R + r0 + cc * 4) = w;
  }
}

// ---------------- grouped GEMM (128x128 tile, BK=32, global_load_lds w16, XOR-swizzled LDS) ----
// FIRST : h[pair][D] = relu( x_bf[tok(pair)][H] @ w1t[e][D][H]^T + b1[e] ), bf16 store
// !FIRST: ypair[split][pair][H] = h[pair][D(split)] @ w2t[e][H][D]^T  (raw fp32, no bias/scale)
// LDS swizzle: lane t stages global 16B-chunk (row=t>>2, kc=(t&3)^((t>>3)&3)) at slot t.
// Fragment read: chunk (row, fg) lives at row*32 + (fg^((fr>>1)&3))*8 -> all-8-distinct
// bank groups per 8-lane phase (conflict-free b128).

template <bool FIRST>
__global__ __launch_bounds__(256, 2) void moe_gemm(
    const u16* __restrict__ A, const u16* __restrict__ Bw, const float* __restrict__ bias,
    const int* __restrict__ ptok, const int* __restrict__ offs,
    u16* __restrict__ Hout, float* __restrict__ Y) {
  constexpr int KD = FIRST ? H_DIM : D_DIM;    // total reduction dim
  constexpr int KSPAN = FIRST ? KD : KD / 2;   // per-launch K span (split-K=2 for GEMM2)
  constexpr int ND = FIRST ? D_DIM : H_DIM;    // output cols
  constexpr int AS = FIRST ? H_DIM : D_DIM;    // A row stride

  const int row0 = blockIdx.y * 128;
  const int total = offs[8];
  if (row0 >= total) return;
  int e = 0;
  #pragma unroll
  for (int q = 0; q < 7; q++) if (row0 >= offs[q + 1]) e = q + 1;

  const int n0 = blockIdx.x * 128;
  const int t = threadIdx.x;
  const int kbase = FIRST ? 0 : (int)blockIdx.z * KSPAN;

  __shared__ __align__(16) u16 lA[128 * 32];
  __shared__ __align__(16) u16 lB[128 * 32];

  const int rA0 = row0 + (t >> 2);
  const int rA1 = rA0 + 64;
  size_t aoff0, aoff1;
  if (FIRST) {
    aoff0 = (size_t)ptok[rA0] * AS;
    aoff1 = (size_t)ptok[rA1] * AS;
  } else {
    aoff0 = (size_t)rA0 * AS;
    aoff1 = (size_t)rA1 * AS;
  }
  const int kc = (((t & 3) ^ ((t >> 3) & 3))) * 8;   // swizzled 16B chunk within BK=32
  const u16* gA0 = A + aoff0 + kbase + kc;
  const u16* gA1 = A + aoff1 + kbase + kc;
  const u16* Be = Bw + (size_t)e * (H_DIM * D_DIM);
  const u16* gB0 = Be + (size_t)(n0 + (t >> 2)) * KD + kbase + kc;
  const u16* gB1 = gB0 + (size_t)64 * KD;
  u16* dA0 = &lA[t * 8];       u16* dA1 = &lA[(t + 256) * 8];
  u16* dB0 = &lB[t * 8];       u16* dB1 = &lB[(t + 256) * 8];

  const int wave = t >> 6, lane = t & 63;
  const int wr = (wave >> 1) * 64, wc = (wave & 1) * 64;
  const int fr = lane & 15, fg = lane >> 4;
  const int sw = (fg ^ ((fr >> 1) & 3)) * 8;         // swizzled fragment chunk offset

  floatx4 acc[4][4];
  #pragma unroll
  for (int i = 0; i < 4; i++)
    #pragma unroll
    for (int j = 0; j < 4; j++) acc[i][j] = (floatx4){0.f, 0.f, 0.f, 0.f};

  for (int k0 = 0; k0 < KSPAN; k0 += 32) {
    gload_lds16(gA0 + k0, dA0);
    gload_lds16(gA1 + k0, dA1);
    gload_lds16(gB0 + k0, dB0);
    gload_lds16(gB1 + k0, dB1);
    __syncthreads();
    short8 af[4], bf[4];
    #pragma unroll
    for (int i = 0; i < 4; i++) af[i] = *(const short8*)&lA[(wr + i * 16 + fr) * 32 + sw];
    #pragma unroll
    for (int j = 0; j < 4; j++) bf[j] = *(const short8*)&lB[(wc + j * 16 + fr) * 32 + sw];
    #pragma unroll
    for (int i = 0; i < 4; i++)
      #pragma unroll
      for (int j = 0; j < 4; j++)
        acc[i][j] = __builtin_amdgcn_mfma_f32_16x16x32_bf16(af[i], bf[j], acc[i][j], 0, 0, 0);
    __syncthreads();
  }

  if (FIRST) {
    const float* be = bias + (size_t)e * ND;
    #pragma unroll
    for (int i = 0; i < 4; i++) {
      #pragma unroll
      for (int r = 0; r < 4; r++) {
        int row = row0 + wr + i * 16 + fg * 4 + r;
        u16* hrow = Hout + (size_t)row * ND;
        #pragma unroll
        for (int j = 0; j < 4; j++) {
          int col = n0 + wc + j * 16 + fr;
          float v = acc[i][j][r] + be[col];
          hrow[col] = f2bf(fmaxf(v, 0.f));
        }
      }
    }
  } else {
    float* yp = Y + (size_t)blockIdx.z * ((size_t)PAIR_CAP * H_DIM);
    #pragma unroll
    for (int i = 0; i < 4; i++) {
      #pragma unroll
      for (int r = 0; r < 4; r++) {
        int row = row0 + wr + i * 16 + fg * 4 + r;
        float* yrow = yp + (size_t)row * ND;
        #pragma unroll
        for (int j = 0; j < 4; j++) {
          int col = n0 + wc + j * 16 + fr;
          yrow[col] = acc[i][j][r];
        }
      }
    }
  }
}

// ---------------- combine: y[tok] = sum_k scale_k * (part0 + part1 + b2[e_k]) ----------------

__global__ __launch_bounds__(256) void combine_kernel(
    const float* __restrict__ yp, const int* __restrict__ pairpos,
    const float* __restrict__ pscale, const int* __restrict__ pexp,
    const float* __restrict__ b2, float* __restrict__ y) {
  const size_t SS = (size_t)PAIR_CAP * H_DIM;
  int tok = blockIdx.x;
  int c = threadIdx.x * 4;
  int p0 = pairpos[2 * tok], p1 = pairpos[2 * tok + 1];
  float s0 = pscale[p0], s1 = pscale[p1];
  float4 a0 = *(const float4*)(yp + (size_t)p0 * H_DIM + c);
  float4 a1 = *(const float4*)(yp + SS + (size_t)p0 * H_DIM + c);
  float4 a2 = *(const float4*)(yp + (size_t)p1 * H_DIM + c);
  float4 a3 = *(const float4*)(yp + SS + (size_t)p1 * H_DIM + c);
  float4 q0 = *(const float4*)(b2 + (size_t)pexp[p0] * H_DIM + c);
  float4 q1 = *(const float4*)(b2 + (size_t)pexp[p1] * H_DIM + c);
  float4 r;
  r.x = s0 * (a0.x + a1.x + q0.x) + s1 * (a2.x + a3.x + q1.x);
  r.y = s0 * (a0.y + a1.y + q0.y) + s1 * (a2.y + a3.y + q1.y);
  r.z = s0 * (a0.z + a1.z + q0.z) + s1 * (a2.z + a3.z + q1.z);
  r.w = s0 * (a0.w + a1.w + q0.w) + s1 * (a2.w + a3.w + q1.w);
  *(float4*)(y + (size_t)tok * H_DIM + c) = r;
}

// ---------------- launch ----------------

extern "C" void kernel_launch(void* const* d_in, const int* in_sizes, int n_in,
                              void* d_out, int out_size, void* d_ws, size_t ws_size,
                              hipStream_t stream) {
  const float* x      = (const float*)d_in[0];
  const float* gate_w = (const float*)d_in[1];
  const float* gate_b = (const float*)d_in[2];
  const float* w1     = (const float*)d_in[3];
  const float* b1     = (const float*)d_in[4];
  const float* w2     = (const float*)d_in[5];
  const float* b2     = (const float*)d_in[6];
  float* out = (float*)d_out;

  char* ws = (char*)d_ws;
  // ypair ([2][PAIR_CAP][H] fp32 = 75,497,472 B) aliases x_bf+w1t, which are
  // dead once GEMM1 completes (stream-ordered before GEMM2).
  u16*   x_bf   = (u16*)  (ws);                 //   8,388,608 B
  u16*   w1t    = (u16*)  (ws + 8388608);       //  67,108,864 B  [E][D][H]
  float* ypair  = (float*)(ws);                 //  75,497,472 B  [2][PAIR_CAP][H]
  u16*   w2t    = (u16*)  (ws + 75497472);      //  67,108,864 B  [E][H][D]
  u16*   h_bf   = (u16*)  (ws + 142606336);     //  75,497,472 B  [PAIR_CAP][D]
  int*   ptok   = (int*)  (ws + 218103808);     //  PAIR_CAP ints
  float* pscale = (float*)(ws + 218140672);     //  PAIR_CAP floats
  int*   tidx   = (int*)  (ws + 218177536);     //  B*2 ints
  float* tscale = (float*)(ws + 218210304);     //  B*2 floats
  int*   ctr    = (int*)  (ws + 218243072);
  int*   fill     = ctr;            // [0..7]
  int*   offs     = ctr + 8;        // [8..16]
  int*   pcnt     = ctr + 32;       // GATE_BLOCKS*8 ints
  float* psum     = (float*)(ctr + 32 + GATE_BLOCKS * 8);
  int*   pairpos  = (int*)  (ws + 218300416);   //  B*2 ints
  int*   pexp     = (int*)  (ws + 218333184);   //  PAIR_CAP ints

  hipMemsetAsync(fill, 0, 8 * sizeof(int), stream);

  convert_x<<<(B_TOK * H_DIM) / 4 / 256, 256, 0, stream>>>(x, x_bf);
  transpose_convert<<<dim3(D_DIM / 64, H_DIM / 64, E_NUM), 256, 0, stream>>>(w1, w1t, H_DIM, D_DIM);
  transpose_convert<<<dim3(H_DIM / 64, D_DIM / 64, E_NUM), 256, 0, stream>>>(w2, w2t, D_DIM, H_DIM);
  gate_kernel<<<GATE_BLOCKS, 256, 0, stream>>>(x, gate_w, gate_b, pcnt, psum, tidx, tscale);
  offsets_kernel<<<1, 256, 0, stream>>>(pcnt, psum, offs, ptok, out + (size_t)B_TOK * H_DIM);
  scatter_kernel<<<B_TOK / 256, 256, 0, stream>>>(tidx, tscale, offs, fill, ptok, pscale, pexp, pairpos);
  moe_gemm<true><<<dim3(D_DIM / 128, PAIR_CAP / 128, 1), 256, 0, stream>>>(
      x_bf, w1t, b1, ptok, offs, h_bf, nullptr);
  moe_gemm<false><<<dim3(H_DIM / 128, PAIR_CAP / 128, 2), 256, 0, stream>>>(
      h_bf, w2t, nullptr, ptok, offs, nullptr, ypair);
  combine_kernel<<<B_TOK, 256, 0, stream>>>(ypair, pairpos, pscale, pexp, b2, out);
}